// Round 2
// baseline (1801.726 us; speedup 1.0000x reference)
//
#include <hip/hip_runtime.h>
#include <math.h>

// ---------------------------------------------------------------------------
// QCNN+QLSTM+QSampler fused forward.
//   out layout: [0,B)   qcnn  (B,1)
//               [B,11B) tag   (B,1,10)
//               [11B,15B) samp (B,4)
//   ws: B*16 floats of LSTM hidden states (outs), consumed by k_tag.
//
// R2: serial scan rebuilt LDS-free. All cross-lane traffic on the VALU pipe:
//   - h all-gather: 4-level row_ror DPP butterfly (direction probed at runtime,
//     weights permuted to match)
//   - qlayer: inclusive-prefix (row_shr KS) + suffix (row_shl KS), no bpermute
//   - gate gather: permlane32_swap + 2x permlane16_swap, output order
//     disambiguated by bitwise own-value compare (robust to either HW order)
// ---------------------------------------------------------------------------

typedef unsigned int uint32x2 __attribute__((ext_vector_type(2)));

__device__ __forceinline__ float2 cmulf(float2 a, float2 b){
  return make_float2(a.x*b.x - a.y*b.y, a.x*b.y + a.y*b.x);
}

// DPP move: result = src[dpp-mapped lane]; out-of-bounds lanes keep `old`.
template<int CTRL>
__device__ __forceinline__ float dpp_mov(float v){
  return __int_as_float(__builtin_amdgcn_update_dpp(
      0, __float_as_int(v), CTRL, 0xF, 0xF, false));
}
template<int CTRL>
__device__ __forceinline__ float dpp_or_one(float v){
  return __int_as_float(__builtin_amdgcn_update_dpp(
      __float_as_int(1.0f), __float_as_int(v), CTRL, 0xF, 0xF, false));
}
// ctrl encodings: row_shl:D = 0x100|D, row_shr:D = 0x110|D, row_ror:D = 0x120|D

// ---------------- 8-qubit statevector: 64 lanes x 4 amplitudes -------------
// amp index i (8 bits), qubit q bit = (i >> (7-q)) & 1 ; lane = i>>2, r = i&3.

__device__ __forceinline__ void apply_diag(float2 (&s)[4], int q, float2 d0, float2 d1){
  const int lane = threadIdx.x;
  #pragma unroll
  for (int r=0;r<4;r++){
    int bit = (q>=6) ? ((r >> (7-q)) & 1) : ((lane >> (5-q)) & 1);
    s[r] = cmulf(s[r], bit ? d1 : d0);
  }
}

__device__ __forceinline__ void apply_real(float2 (&s)[4], int q,
                                           float m00, float m01, float m10, float m11){
  const int lane = threadIdx.x;
  if (q >= 6){
    const int st = 1 << (7-q);
    for (int base=0;base<4;base++){
      if (base & st) continue;
      float2 a = s[base], b2 = s[base+st];
      s[base]    = make_float2(fmaf(m00,a.x, m01*b2.x), fmaf(m00,a.y, m01*b2.y));
      s[base+st] = make_float2(fmaf(m10,a.x, m11*b2.x), fmaf(m10,a.y, m11*b2.y));
    }
  } else {
    const int mask = 1 << (5-q);
    const bool hi = (lane & mask) != 0;
    #pragma unroll
    for (int r=0;r<4;r++){
      float ox = __shfl_xor(s[r].x, mask);
      float oy = __shfl_xor(s[r].y, mask);
      float2 m = s[r];
      if (!hi) s[r] = make_float2(fmaf(m00,m.x, m01*ox), fmaf(m00,m.y, m01*oy));
      else     s[r] = make_float2(fmaf(m10,ox, m11*m.x), fmaf(m10,oy, m11*m.y));
    }
  }
}

__device__ __forceinline__ void cnot_g(float2 (&s)[4], int c, int t){
  const int lane = threadIdx.x;
  if (t >= 6){
    const int st = 1 << (7-t);
    for (int base=0;base<4;base++){
      if (base & st) continue;
      int cb = (c>=6) ? ((base >> (7-c)) & 1) : ((lane >> (5-c)) & 1);
      if (cb){ float2 tmp=s[base]; s[base]=s[base+st]; s[base+st]=tmp; }
    }
  } else {
    const int mask = 1 << (5-t);
    #pragma unroll
    for (int r=0;r<4;r++){
      float ox = __shfl_xor(s[r].x, mask);
      float oy = __shfl_xor(s[r].y, mask);
      int cb = (c>=6) ? ((r >> (7-c)) & 1) : ((lane >> (5-c)) & 1);
      if (cb) s[r] = make_float2(ox, oy);
    }
  }
}

__device__ void conv_g(float2 (&s)[4], int qa, int qb, const float* p){
  const float R = 0.70710678118654752f;
  apply_diag(s, qb, make_float2(R,R), make_float2(R,-R));      // rz(-pi/2)
  cnot_g(s, qb, qa);
  float sn, cs;
  __sincosf(0.5f*p[0], &sn, &cs);
  apply_diag(s, qa, make_float2(cs,-sn), make_float2(cs,sn));  // rz(p0)
  __sincosf(0.5f*p[1], &sn, &cs);
  apply_real(s, qb, cs, -sn, sn, cs);                          // ry(p1)
  cnot_g(s, qa, qb);
  __sincosf(0.5f*p[2], &sn, &cs);
  apply_real(s, qb, cs, -sn, sn, cs);                          // ry(p2)
  cnot_g(s, qb, qa);
  apply_diag(s, qa, make_float2(R,-R), make_float2(R,R));      // rz(pi/2)
}

__device__ void pool_g(float2 (&s)[4], int qa, int qb, const float* p){
  const float R = 0.70710678118654752f;
  apply_diag(s, qb, make_float2(R,R), make_float2(R,-R));      // rz(-pi/2)
  cnot_g(s, qb, qa);
  float sn, cs;
  __sincosf(0.5f*p[0], &sn, &cs);
  apply_diag(s, qa, make_float2(cs,-sn), make_float2(cs,sn));  // rz(p0)
  __sincosf(0.5f*p[1], &sn, &cs);
  apply_real(s, qb, cs, -sn, sn, cs);                          // ry(p1)
  cnot_g(s, qa, qb);
  __sincosf(0.5f*p[2], &sn, &cs);
  apply_real(s, qb, cs, -sn, sn, cs);                          // ry(p2)
}

// robust pair split for permlane*_swap outputs: {r0,r1} = {x[low], x[high]}
// in unknown order; `own` is x at this lane, `ownIsLow` says which side we are.
__device__ __forceinline__ void pair_split(unsigned own, bool ownIsLow,
                                           unsigned r0, unsigned r1,
                                           float& lo, float& hi){
  unsigned other = (r0 == own) ? r1 : r0;
  lo = __uint_as_float(ownIsLow ? own   : other);
  hi = __uint_as_float(ownIsLow ? other : own);
}

// ---------------------------------------------------------------------------

extern "C" __global__ void __launch_bounds__(64)
k_fused(const float* __restrict__ inputs,
        const float* __restrict__ c1, const float* __restrict__ p1,
        const float* __restrict__ c2, const float* __restrict__ p2,
        const float* __restrict__ c3, const float* __restrict__ p3,
        const float* __restrict__ w_smp,
        const float* __restrict__ Wf, const float* __restrict__ bfv,
        const float* __restrict__ Wi, const float* __restrict__ biv,
        const float* __restrict__ Wu, const float* __restrict__ buv,
        const float* __restrict__ Wo, const float* __restrict__ bov,
        const float* __restrict__ thf, const float* __restrict__ thi,
        const float* __restrict__ thu, const float* __restrict__ tho,
        float* __restrict__ out, float* __restrict__ ws, int B)
{
  const int lane = threadIdx.x;

  if (blockIdx.x == 0){
    // ------------- sequential qLSTM scan over B steps (single wave) --------
    const int g = lane >> 4, e = lane & 15;   // gate (f,i,u,o), element
    const float* W  = (g==0)?Wf :(g==1)?Wi :(g==2)?Wu :Wo;
    const float* bb = (g==0)?bfv:(g==1)?biv:(g==2)?buv:bov;
    const float* th = (g==0)?thf:(g==1)?thi:(g==2)?thu:tho;

    // probe row_ror direction once: reg after ror:d holds h[(e + sgn*d)&15]
    int probe = __builtin_amdgcn_update_dpp(0, e, 0x121, 0xF, 0xF, false);
    const int sgn = (probe == ((e+1)&15)) ? 1 : -1;

    float wx[8], wh[16];
    #pragma unroll
    for (int k=0;k<8;k++)  wx[k] = W[e*24+k];
    #pragma unroll
    for (int d=0;d<16;d++) wh[d] = W[e*24+8 + ((e + sgn*d + 32) & 15)];
    const float bias  = bb[e];
    const float theta = th[e];
    // activation constants: sigmoid for f,i,o ; tanh (=2*sig(2v)-1) for u
    const float esc = (g==2) ? -2.88539008f : -1.44269504f;  // -scale*log2(e)
    const float gA  = (g==2) ? 2.0f : 1.0f;
    const float gB  = (g==2) ? -1.0f : 0.0f;
    const bool isLow32 = (lane & 32) == 0;
    const bool isLow16 = (lane & 16) == 0;

    float cx = 0.0f, h = 0.0f;
    float4 xA = *(const float4*)(inputs);
    float4 xB = *(const float4*)(inputs + 4);
    float4 yA = *(const float4*)(inputs + 8);
    float4 yB = *(const float4*)(inputs + 12);
    for (int t=0; t<B; t++){
      // 2-deep x prefetch (uniform address -> broadcast load, L2-resident)
      int tn = t + 2; if (tn > B-1) tn = B-1;
      float4 zA = *(const float4*)(inputs + tn*8);
      float4 zB = *(const float4*)(inputs + tn*8 + 4);

      // ---- h all-gather via row_ror butterfly (VALU pipe only) ----
      const float h0  = h;
      const float h8  = dpp_mov<0x128>(h0);
      const float h4  = dpp_mov<0x124>(h0);
      const float h12 = dpp_mov<0x124>(h8);
      const float h2  = dpp_mov<0x122>(h0);
      const float h6  = dpp_mov<0x122>(h4);
      const float h10 = dpp_mov<0x122>(h8);
      const float h14 = dpp_mov<0x122>(h12);
      const float h1  = dpp_mov<0x121>(h0);
      const float h3  = dpp_mov<0x121>(h2);
      const float h5  = dpp_mov<0x121>(h4);
      const float h7  = dpp_mov<0x121>(h6);
      const float h9  = dpp_mov<0x121>(h8);
      const float h11 = dpp_mov<0x121>(h10);
      const float h13 = dpp_mov<0x121>(h12);
      const float h15 = dpp_mov<0x121>(h14);

      // x-part runs in parallel with the DPP chain (independent)
      float a0 = fmaf(wx[0], xA.x, bias);
      float a1 = wx[1]*xA.y;
      float a2 = wx[2]*xA.z;
      float a3 = wx[3]*xA.w;
      a0 = fmaf(wx[4], xB.x, a0); a1 = fmaf(wx[5], xB.y, a1);
      a2 = fmaf(wx[6], xB.z, a2); a3 = fmaf(wx[7], xB.w, a3);
      // h-part, in register-availability order
      a0 = fmaf(wh[0],  h0,  a0); a1 = fmaf(wh[8],  h8,  a1);
      a2 = fmaf(wh[4],  h4,  a2); a3 = fmaf(wh[12], h12, a3);
      a0 = fmaf(wh[2],  h2,  a0); a1 = fmaf(wh[10], h10, a1);
      a2 = fmaf(wh[6],  h6,  a2); a3 = fmaf(wh[14], h14, a3);
      a0 = fmaf(wh[1],  h1,  a0); a1 = fmaf(wh[9],  h9,  a1);
      a2 = fmaf(wh[5],  h5,  a2); a3 = fmaf(wh[13], h13, a3);
      a0 = fmaf(wh[3],  h3,  a0); a1 = fmaf(wh[11], h11, a1);
      a2 = fmaf(wh[7],  h7,  a2); a3 = fmaf(wh[15], h15, a3);
      const float acc = ((a0+a1) + (a2+a3)) + theta;

      // ---- qlayer: v[e>=1] = prod_{0..e} c ; v[0] = prod_{1..15} c ----
      const float c = __cosf(acc);
      float p = c;                               // inclusive prefix (row_shr)
      p *= dpp_or_one<0x111>(p);
      p *= dpp_or_one<0x112>(p);
      p *= dpp_or_one<0x114>(p);
      p *= dpp_or_one<0x118>(p);
      float sfx = (e==0) ? 1.0f : c;             // suffix (row_shl), c0 := 1
      sfx *= dpp_or_one<0x101>(sfx);
      sfx *= dpp_or_one<0x102>(sfx);
      sfx *= dpp_or_one<0x104>(sfx);
      sfx *= dpp_or_one<0x108>(sfx);
      const float v = (e==0) ? sfx : p;

      // ---- activation (one exp per lane) ----
      const float ex  = __builtin_amdgcn_exp2f(v * esc);
      const float sg  = __builtin_amdgcn_rcpf(1.0f + ex);
      const float act = fmaf(gA, sg, gB);

      // ---- gate gather: permlane swaps (VALU pipe) ----
      const unsigned au = __float_as_uint(act);
      uint32x2 r32 = __builtin_amdgcn_permlane32_swap(au, au, false, false);
      float vLo, vHi;               // act at gate (g&1) / gate (g|2), this e
      pair_split(au, isLow32, r32[0], r32[1], vLo, vHi);
      const unsigned uLo = __float_as_uint(vLo);
      const unsigned uHi = __float_as_uint(vHi);
      uint32x2 rA = __builtin_amdgcn_permlane16_swap(uLo, uLo, false, false);
      uint32x2 rB = __builtin_amdgcn_permlane16_swap(uHi, uHi, false, false);
      float f, iw, u, o;
      pair_split(uLo, isLow16, rA[0], rA[1], f,  iw);  // gates 0,1
      pair_split(uHi, isLow16, rB[0], rB[1], u,  o);   // gates 2,3

      // ---- state update ----
      cx = fmaf(f, cx, iw*u);
      const float em = __builtin_amdgcn_exp2f(cx * -2.88539008f);
      const float rr = __builtin_amdgcn_rcpf(1.0f + em);
      h = fmaf(o+o, rr, -o);        // o * tanh(cx)

      if (lane < 16) ws[t*16 + lane] = h;
      xA = yA; xB = yB; yA = zA; yB = zB;
    }
    return;
  }

  // ---------------- QCNN (one wave per sample) + sampler -------------------
  const int b = blockIdx.x - 1;
  float2 s[4];
  s[0] = make_float2(0.f,0.f); s[1]=s[0]; s[2]=s[0]; s[3]=s[0];
  if (lane == 0) s[0] = make_float2(1.f, 0.f);
  float xl[8];
  #pragma unroll
  for (int k=0;k<8;k++) xl[k] = inputs[b*8+k];
  const float R = 0.70710678118654752f;
  for (int rep=0;rep<2;rep++){
    for (int q=0;q<8;q++) apply_real(s, q, R, R, R, -R);       // H
    for (int q=0;q<8;q++){
      float sn, cs; __sincosf(2.0f*xl[q], &sn, &cs);
      apply_diag(s, q, make_float2(1.f,0.f), make_float2(cs,sn)); // phase(2x)
    }
  }
  for (int k=0;k<4;k++) conv_g(s, 2*k, 2*k+1, c1+3*k);
  for (int k=0;k<4;k++) pool_g(s, k, k+4, p1+3*k);
  for (int k=0;k<2;k++) conv_g(s, 2*k, 2*k+1, c2+3*k);
  for (int k=0;k<2;k++) pool_g(s, k, k+2, p2+3*k);
  conv_g(s, 0, 1, c3);
  pool_g(s, 0, 1, p3);
  // expZ on qubit 7 (r bit0)
  float v = (s[0].x*s[0].x + s[0].y*s[0].y) - (s[1].x*s[1].x + s[1].y*s[1].y)
          + (s[2].x*s[2].x + s[2].y*s[2].y) - (s[3].x*s[3].x + s[3].y*s[3].y);
  #pragma unroll
  for (int d=1; d<64; d<<=1) v += __shfl_xor(v, d);
  if (lane == 0){
    out[b] = v;
    // ---- 2-qubit real sampler ----
    float a00=1.f, a01=0.f, a10=0.f, a11=0.f;
    float sn, cs, t0, t1;
    #define RY0(T) { __sincosf(0.5f*(T), &sn, &cs); \
      t0 = cs*a00 - sn*a10; t1 = sn*a00 + cs*a10; a00=t0; a10=t1; \
      t0 = cs*a01 - sn*a11; t1 = sn*a01 + cs*a11; a01=t0; a11=t1; }
    #define RY1(T) { __sincosf(0.5f*(T), &sn, &cs); \
      t0 = cs*a00 - sn*a01; t1 = sn*a00 + cs*a01; a00=t0; a01=t1; \
      t0 = cs*a10 - sn*a11; t1 = sn*a10 + cs*a11; a10=t0; a11=t1; }
    #define CN01 { float tmp=a10; a10=a11; a11=tmp; }
    RY0(xl[0]); RY1(xl[1]); CN01;
    RY0(w_smp[0]); RY1(w_smp[1]); CN01;
    RY0(w_smp[2]); RY1(w_smp[3]);
    #undef RY0
    #undef RY1
    #undef CN01
    float* samp = out + B + B*10;
    samp[b*4+0] = a00*a00; samp[b*4+1] = a10*a10;
    samp[b*4+2] = a01*a01; samp[b*4+3] = a11*a11;
  }
}

// tag = log_softmax(outs @ Wt.T + bt), parallel over B
extern "C" __global__ void __launch_bounds__(256)
k_tag(const float* __restrict__ hs, const float* __restrict__ Wt,
      const float* __restrict__ bt, float* __restrict__ tag, int B)
{
  const int b = blockIdx.x*blockDim.x + threadIdx.x;
  if (b >= B) return;
  const float4* hp = (const float4*)(hs + b*16);
  const float4 h0=hp[0], h1=hp[1], h2=hp[2], h3=hp[3];
  float lg[10];
  #pragma unroll
  for (int j=0;j<10;j++){
    const float* w = Wt + j*16;
    float s0 = fmaf(w[0],h0.x, bt[j]); s0=fmaf(w[4],h1.x,s0); s0=fmaf(w[8],h2.x,s0);  s0=fmaf(w[12],h3.x,s0);
    float s1 = w[1]*h0.y;              s1=fmaf(w[5],h1.y,s1); s1=fmaf(w[9],h2.y,s1);  s1=fmaf(w[13],h3.y,s1);
    float s2 = w[2]*h0.z;              s2=fmaf(w[6],h1.z,s2); s2=fmaf(w[10],h2.z,s2); s2=fmaf(w[14],h3.z,s2);
    float s3 = w[3]*h0.w;              s3=fmaf(w[7],h1.w,s3); s3=fmaf(w[11],h2.w,s3); s3=fmaf(w[15],h3.w,s3);
    lg[j] = (s0+s1)+(s2+s3);
  }
  float m = lg[0];
  #pragma unroll
  for (int j=1;j<10;j++) m = fmaxf(m, lg[j]);
  float ss = 0.f;
  #pragma unroll
  for (int j=0;j<10;j++) ss += __expf(lg[j]-m);
  const float lse = __logf(ss) + m;
  #pragma unroll
  for (int j=0;j<10;j++) tag[b*10+j] = lg[j] - lse;
}

extern "C" void kernel_launch(void* const* d_in, const int* in_sizes, int n_in,
                              void* d_out, int out_size, void* d_ws, size_t ws_size,
                              hipStream_t stream)
{
  const float* inputs = (const float*)d_in[0];
  const float* c1  = (const float*)d_in[1];
  const float* p1  = (const float*)d_in[2];
  const float* c2  = (const float*)d_in[3];
  const float* p2  = (const float*)d_in[4];
  const float* c3  = (const float*)d_in[5];
  const float* p3  = (const float*)d_in[6];
  const float* wsm = (const float*)d_in[7];
  const float* Wf  = (const float*)d_in[8];
  const float* bf_ = (const float*)d_in[9];
  const float* Wi  = (const float*)d_in[10];
  const float* bi_ = (const float*)d_in[11];
  const float* Wu  = (const float*)d_in[12];
  const float* bu_ = (const float*)d_in[13];
  const float* Wo  = (const float*)d_in[14];
  const float* bo_ = (const float*)d_in[15];
  const float* thf = (const float*)d_in[16];
  const float* thi = (const float*)d_in[17];
  const float* thu = (const float*)d_in[18];
  const float* tho = (const float*)d_in[19];
  const float* Wt  = (const float*)d_in[20];
  const float* bt  = (const float*)d_in[21];
  const int B = in_sizes[0] / 8;          // 4096
  float* out = (float*)d_out;
  float* ws  = (float*)d_ws;              // needs B*16*4 = 256 KiB scratch

  k_fused<<<B+1, 64, 0, stream>>>(inputs, c1,p1,c2,p2,c3,p3, wsm,
                                  Wf,bf_,Wi,bi_,Wu,bu_,Wo,bo_,
                                  thf,thi,thu,tho, out, ws, B);
  k_tag<<<(B+255)/256, 256, 0, stream>>>(ws, Wt, bt, out + B, B);
}

// Round 4
// 1026.179 us; speedup vs baseline: 1.7558x; 1.7558x over previous
//
#include <hip/hip_runtime.h>
#include <math.h>

// ---------------------------------------------------------------------------
// QCNN+QLSTM+QSampler forward, R4 (= R3 + act3 gather-select fix).
//   out: [0,B) qcnn | [B,11B) tag | [11B,15B) samp
//   ws : [0, B*64) ax (float, [B/4][64] float4 layout)  |  [B*64, B*80) h
// Dispatches: k_pre (parallel ax) -> k_serial (1 wave scan, zero per-step
// vmem on critical path) -> k_qcnn -> k_tag.
// ---------------------------------------------------------------------------

typedef unsigned int uint32x2 __attribute__((ext_vector_type(2)));

__device__ __forceinline__ float2 cmulf(float2 a, float2 b){
  return make_float2(a.x*b.x - a.y*b.y, a.x*b.y + a.y*b.x);
}
template<int CTRL>
__device__ __forceinline__ float dpp_mov(float v){
  return __int_as_float(__builtin_amdgcn_update_dpp(
      0, __float_as_int(v), CTRL, 0xF, 0xF, false));
}
template<int CTRL>
__device__ __forceinline__ float dpp_or_one(float v){
  return __int_as_float(__builtin_amdgcn_update_dpp(
      __float_as_int(1.0f), __float_as_int(v), CTRL, 0xF, 0xF, false));
}
// row_shl:D = 0x100|D, row_shr:D = 0x110|D, row_ror:D = 0x120|D

// ---------------- serial LSTM step (shared core) ---------------------------
struct SerState {
  float wh[16];
  float esc, gA, gB;
  int   lane, e;
  bool  c32, c16, b0, b1, mQ;
};

__device__ __forceinline__ void lstm_step(const SerState& S, float ax,
                                          float& cx, float& h){
  // h all-gather: 4-level row_ror DPP tree (VALU pipe). v_d = h[(e+sgn*d)&15],
  // weights were pre-permuted to match.
  const float v0  = h;
  const float v8  = dpp_mov<0x128>(v0);
  const float v4  = dpp_mov<0x124>(v0);
  const float v12 = dpp_mov<0x124>(v8);
  const float v2  = dpp_mov<0x122>(v0);
  const float v6  = dpp_mov<0x122>(v4);
  const float v10 = dpp_mov<0x122>(v8);
  const float v14 = dpp_mov<0x122>(v12);
  const float v1  = dpp_mov<0x121>(v0);
  const float v3  = dpp_mov<0x121>(v2);
  const float v5  = dpp_mov<0x121>(v4);
  const float v7  = dpp_mov<0x121>(v6);
  const float v9  = dpp_mov<0x121>(v8);
  const float v11 = dpp_mov<0x121>(v10);
  const float v13 = dpp_mov<0x121>(v12);
  const float v15 = dpp_mov<0x121>(v14);
  float a0 = fmaf(S.wh[0], v0, ax);
  float a1 = S.wh[8]  * v8;
  float a2 = S.wh[4]  * v4;
  float a3 = S.wh[12] * v12;
  a0 = fmaf(S.wh[2],  v2,  a0);  a1 = fmaf(S.wh[10], v10, a1);
  a2 = fmaf(S.wh[6],  v6,  a2);  a3 = fmaf(S.wh[14], v14, a3);
  a0 = fmaf(S.wh[1],  v1,  a0);  a1 = fmaf(S.wh[9],  v9,  a1);
  a2 = fmaf(S.wh[5],  v5,  a2);  a3 = fmaf(S.wh[13], v13, a3);
  a0 = fmaf(S.wh[3],  v3,  a0);  a1 = fmaf(S.wh[11], v11, a1);
  a2 = fmaf(S.wh[7],  v7,  a2);  a3 = fmaf(S.wh[15], v15, a3);
  const float acc = (a0+a1) + (a2+a3);        // ax already holds b+theta+x.wx

  // qlayer: v[e>=1] = prod_{0..e} c ; v[0] = prod_{1..15} c
  const float c = __cosf(acc);
  float p = c;
  p *= dpp_or_one<0x111>(p);
  p *= dpp_or_one<0x112>(p);
  p *= dpp_or_one<0x114>(p);
  p *= dpp_or_one<0x118>(p);
  float sfx = (S.e==0) ? 1.0f : c;
  sfx *= dpp_or_one<0x101>(sfx);
  sfx *= dpp_or_one<0x102>(sfx);
  sfx *= dpp_or_one<0x104>(sfx);
  sfx *= dpp_or_one<0x108>(sfx);
  const float v = (S.e==0) ? sfx : p;

  // activation: sigmoid (f,i,o) / tanh (u) via one exp2+rcp
  const float ex  = __builtin_amdgcn_exp2f(v * S.esc);
  const float sg  = __builtin_amdgcn_rcpf(1.0f + ex);
  const float act = fmaf(S.gA, sg, S.gB);

  // gate gather: values at xor-distance {0,1,2,3} from my gate g
  const unsigned au = __float_as_uint(act);
  uint32x2 r32 = __builtin_amdgcn_permlane32_swap(au, au, false, false);
  const unsigned o32u = S.c32 ? r32[0] : r32[1];          // dist 2
  uint32x2 rA = __builtin_amdgcn_permlane16_swap(au, au, false, false);
  const unsigned oAu = S.c16 ? rA[0] : rA[1];             // dist 1
  uint32x2 rB = __builtin_amdgcn_permlane16_swap(o32u, o32u, false, false);
  const unsigned oBu = S.c16 ? rB[0] : rB[1];             // dist 3
  const float fau = __uint_as_float(au);
  const float fA  = __uint_as_float(oAu);
  const float f32 = __uint_as_float(o32u);
  const float fB  = __uint_as_float(oBu);
  // gate k's value sits at xor-distance (g^k).
  // act0 (f, k=0): dist g      -> g=0:au, 1:fA, 2:f32, 3:fB
  const float act0 = S.b1 ? (S.b0 ? fB  : f32) : (S.b0 ? fA  : fau);
  // act3 (o, k=3): dist g^3    -> g=0:fB, 1:f32, 2:fA, 3:au   [R4 FIX]
  const float act3 = S.b1 ? (S.b0 ? fau : fA ) : (S.b0 ? f32 : fB );
  // i*u = product of values at dist (g^1) and (g^2)
  const float Q = S.mQ ? fA*f32 : fau*fB;

  cx = fmaf(act0, cx, Q);
  const float em = __builtin_amdgcn_exp2f(cx * -2.885390082f);
  const float rr = __builtin_amdgcn_rcpf(1.0f + em);
  h = fmaf(act3+act3, rr, -act3);             // o * tanh(cx)
}

__device__ __forceinline__ void ser_init(SerState& S, int lane,
    const float* Wf, const float* Wi, const float* Wu, const float* Wo){
  const int g = lane >> 4, e = lane & 15;
  S.lane = lane; S.e = e;
  const float* W = (g==0)?Wf:(g==1)?Wi:(g==2)?Wu:Wo;
  // ror direction probe: after ror:1 register holds value from lane (e+sgn)&15
  int probe = __builtin_amdgcn_update_dpp(0, e, 0x121, 0xF, 0xF, false);
  const int sgn = (probe == ((e+1)&15)) ? 1 : -1;
  #pragma unroll
  for (int d=0; d<16; d++) S.wh[d] = W[e*24 + 8 + ((e + sgn*d + 32) & 15)];
  S.esc = (g==2) ? -2.885390082f : -1.442695041f;
  S.gA  = (g==2) ? 2.0f : 1.0f;
  S.gB  = (g==2) ? -1.0f : 0.0f;
  // permlane orientation probes (computed once, reused as cndmasks in-loop)
  uint32x2 p32 = __builtin_amdgcn_permlane32_swap((unsigned)lane,(unsigned)lane,false,false);
  S.c32 = (p32[0] == (unsigned)(lane ^ 32));
  uint32x2 p16 = __builtin_amdgcn_permlane16_swap((unsigned)lane,(unsigned)lane,false,false);
  S.c16 = (p16[0] == (unsigned)(lane ^ 16));
  S.b0 = (g & 1) != 0;
  S.b1 = (g & 2) != 0;
  S.mQ = (g==0) || (g==3);
}

// ---------------- k_pre: ax[t][lane] = b[e]+th[e]+wx.x[t] ------------------
extern "C" __global__ void __launch_bounds__(64)
k_pre(const float* __restrict__ inputs,
      const float* __restrict__ Wf, const float* __restrict__ Wi,
      const float* __restrict__ Wu, const float* __restrict__ Wo,
      const float* __restrict__ bfv, const float* __restrict__ biv,
      const float* __restrict__ buv, const float* __restrict__ bov,
      const float* __restrict__ thf, const float* __restrict__ thi,
      const float* __restrict__ thu, const float* __restrict__ tho,
      float* __restrict__ axws, int B)
{
  const int lane = threadIdx.x, g = lane>>4, e = lane&15;
  const float* W  = (g==0)?Wf :(g==1)?Wi :(g==2)?Wu :Wo;
  const float* bb = (g==0)?bfv:(g==1)?biv:(g==2)?buv:bov;
  const float* th = (g==0)?thf:(g==1)?thi:(g==2)?thu:tho;
  float wx[8];
  #pragma unroll
  for (int k=0;k<8;k++) wx[k] = W[e*24+k];
  const float base = bb[e] + th[e];
  const int t0 = blockIdx.x * 4;
  float4 r;
  #pragma unroll
  for (int q=0;q<4;q++){
    const float4 xa = *(const float4*)(inputs + (t0+q)*8);
    const float4 xb = *(const float4*)(inputs + (t0+q)*8 + 4);
    float a = fmaf(wx[0], xa.x, base);
    a = fmaf(wx[1], xa.y, a); a = fmaf(wx[2], xa.z, a); a = fmaf(wx[3], xa.w, a);
    a = fmaf(wx[4], xb.x, a); a = fmaf(wx[5], xb.y, a);
    a = fmaf(wx[6], xb.z, a); a = fmaf(wx[7], xb.w, a);
    (&r.x)[q] = a;
  }
  ((float4*)axws)[blockIdx.x*64 + lane] = r;   // [B/4][64] float4
}

// ---------------- k_serial: the scan, ax from ws ---------------------------
extern "C" __global__ void __launch_bounds__(64)
k_serial_ax(const float* __restrict__ axws,
            const float* __restrict__ Wf, const float* __restrict__ Wi,
            const float* __restrict__ Wu, const float* __restrict__ Wo,
            float* __restrict__ wsh, int B)
{
  const int lane = threadIdx.x;
  SerState S; ser_init(S, lane, Wf, Wi, Wu, Wo);
  const float4* axp = (const float4*)axws;
  // chunk double-buffer: 16 steps per chunk, next chunk issued 16 steps early
  float4 cb0 = axp[lane], cb1 = axp[64+lane], cb2 = axp[128+lane], cb3 = axp[192+lane];
  float cx = 0.f, h = 0.f, hq0 = 0.f, hq1 = 0.f, hq2 = 0.f;
  for (int t0 = 0; t0 < B; t0 += 16){
    const int nq = (t0+16 < B) ? ((t0+16) >> 2) : (t0 >> 2);
    float4 nb0 = axp[(nq+0)*64 + lane];
    float4 nb1 = axp[(nq+1)*64 + lane];
    float4 nb2 = axp[(nq+2)*64 + lane];
    float4 nb3 = axp[(nq+3)*64 + lane];
    #pragma unroll
    for (int j=0; j<16; j++){
      const float4 cb = (j>>2)==0 ? cb0 : (j>>2)==1 ? cb1 : (j>>2)==2 ? cb2 : cb3;
      const float ax = (j&3)==0 ? cb.x : (j&3)==1 ? cb.y : (j&3)==2 ? cb.z : cb.w;
      lstm_step(S, ax, cx, h);
      if      ((j&3)==0) hq0 = h;
      else if ((j&3)==1) hq1 = h;
      else if ((j&3)==2) hq2 = h;
      else {
        // lane g*16+e stores step t0+j-3+g, elem e: addr collapses to +lane
        const float hv = S.b1 ? (S.b0 ? h : hq2) : (S.b0 ? hq1 : hq0);
        wsh[(t0+j-3)*16 + lane] = hv;          // 256B fully coalesced
      }
    }
    cb0 = nb0; cb1 = nb1; cb2 = nb2; cb3 = nb3;
  }
}

// ---------------- fallback serial (inline x) if ws too small ---------------
extern "C" __global__ void __launch_bounds__(64)
k_serial_x(const float* __restrict__ inputs,
           const float* __restrict__ Wf, const float* __restrict__ Wi,
           const float* __restrict__ Wu, const float* __restrict__ Wo,
           const float* __restrict__ bfv, const float* __restrict__ biv,
           const float* __restrict__ buv, const float* __restrict__ bov,
           const float* __restrict__ thf, const float* __restrict__ thi,
           const float* __restrict__ thu, const float* __restrict__ tho,
           float* __restrict__ wsh, int B)
{
  const int lane = threadIdx.x, g = lane>>4, e = lane&15;
  SerState S; ser_init(S, lane, Wf, Wi, Wu, Wo);
  const float* W  = (g==0)?Wf :(g==1)?Wi :(g==2)?Wu :Wo;
  const float* bb = (g==0)?bfv:(g==1)?biv:(g==2)?buv:bov;
  const float* th = (g==0)?thf:(g==1)?thi:(g==2)?thu:tho;
  float wx[8];
  #pragma unroll
  for (int k=0;k<8;k++) wx[k] = W[e*24+k];
  const float base = bb[e] + th[e];
  float cx=0.f, h=0.f, hq0=0.f, hq1=0.f, hq2=0.f;
  float4 xA = *(const float4*)(inputs),     xB = *(const float4*)(inputs+4);
  float4 yA = *(const float4*)(inputs+8),   yB = *(const float4*)(inputs+12);
  for (int t=0; t<B; t++){
    int tn = t+2; if (tn > B-1) tn = B-1;
    float4 zA = *(const float4*)(inputs + tn*8);
    float4 zB = *(const float4*)(inputs + tn*8 + 4);
    float a = fmaf(wx[0], xA.x, base);
    a = fmaf(wx[1], xA.y, a); a = fmaf(wx[2], xA.z, a); a = fmaf(wx[3], xA.w, a);
    a = fmaf(wx[4], xB.x, a); a = fmaf(wx[5], xB.y, a);
    a = fmaf(wx[6], xB.z, a); a = fmaf(wx[7], xB.w, a);
    lstm_step(S, a, cx, h);
    const int q = t & 3;
    if      (q==0) hq0 = h;
    else if (q==1) hq1 = h;
    else if (q==2) hq2 = h;
    else {
      const float hv = S.b1 ? (S.b0 ? h : hq2) : (S.b0 ? hq1 : hq0);
      wsh[(t-3)*16 + lane] = hv;
    }
    xA = yA; xB = yB; yA = zA; yB = zB;
  }
}

// ---------------- QCNN statevector helpers ---------------------------------
__device__ __forceinline__ void apply_diag(float2 (&s)[4], int q, float2 d0, float2 d1){
  const int lane = threadIdx.x;
  #pragma unroll
  for (int r=0;r<4;r++){
    int bit = (q>=6) ? ((r >> (7-q)) & 1) : ((lane >> (5-q)) & 1);
    s[r] = cmulf(s[r], bit ? d1 : d0);
  }
}
__device__ __forceinline__ void apply_real(float2 (&s)[4], int q,
                                           float m00, float m01, float m10, float m11){
  const int lane = threadIdx.x;
  if (q >= 6){
    const int st = 1 << (7-q);
    for (int base=0;base<4;base++){
      if (base & st) continue;
      float2 a = s[base], b2 = s[base+st];
      s[base]    = make_float2(fmaf(m00,a.x, m01*b2.x), fmaf(m00,a.y, m01*b2.y));
      s[base+st] = make_float2(fmaf(m10,a.x, m11*b2.x), fmaf(m10,a.y, m11*b2.y));
    }
  } else {
    const int mask = 1 << (5-q);
    const bool hi = (lane & mask) != 0;
    #pragma unroll
    for (int r=0;r<4;r++){
      float ox = __shfl_xor(s[r].x, mask);
      float oy = __shfl_xor(s[r].y, mask);
      float2 m = s[r];
      if (!hi) s[r] = make_float2(fmaf(m00,m.x, m01*ox), fmaf(m00,m.y, m01*oy));
      else     s[r] = make_float2(fmaf(m10,ox, m11*m.x), fmaf(m10,oy, m11*m.y));
    }
  }
}
__device__ __forceinline__ void cnot_g(float2 (&s)[4], int c, int t){
  const int lane = threadIdx.x;
  if (t >= 6){
    const int st = 1 << (7-t);
    for (int base=0;base<4;base++){
      if (base & st) continue;
      int cb = (c>=6) ? ((base >> (7-c)) & 1) : ((lane >> (5-c)) & 1);
      if (cb){ float2 tmp=s[base]; s[base]=s[base+st]; s[base+st]=tmp; }
    }
  } else {
    const int mask = 1 << (5-t);
    #pragma unroll
    for (int r=0;r<4;r++){
      float ox = __shfl_xor(s[r].x, mask);
      float oy = __shfl_xor(s[r].y, mask);
      int cb = (c>=6) ? ((r >> (7-c)) & 1) : ((lane >> (5-c)) & 1);
      if (cb) s[r] = make_float2(ox, oy);
    }
  }
}
__device__ void conv_g(float2 (&s)[4], int qa, int qb, const float* p){
  const float R = 0.70710678118654752f;
  apply_diag(s, qb, make_float2(R,R), make_float2(R,-R));
  cnot_g(s, qb, qa);
  float sn, cs;
  __sincosf(0.5f*p[0], &sn, &cs);
  apply_diag(s, qa, make_float2(cs,-sn), make_float2(cs,sn));
  __sincosf(0.5f*p[1], &sn, &cs);
  apply_real(s, qb, cs, -sn, sn, cs);
  cnot_g(s, qa, qb);
  __sincosf(0.5f*p[2], &sn, &cs);
  apply_real(s, qb, cs, -sn, sn, cs);
  cnot_g(s, qb, qa);
  apply_diag(s, qa, make_float2(R,-R), make_float2(R,R));
}
__device__ void pool_g(float2 (&s)[4], int qa, int qb, const float* p){
  const float R = 0.70710678118654752f;
  apply_diag(s, qb, make_float2(R,R), make_float2(R,-R));
  cnot_g(s, qb, qa);
  float sn, cs;
  __sincosf(0.5f*p[0], &sn, &cs);
  apply_diag(s, qa, make_float2(cs,-sn), make_float2(cs,sn));
  __sincosf(0.5f*p[1], &sn, &cs);
  apply_real(s, qb, cs, -sn, sn, cs);
  cnot_g(s, qa, qb);
  __sincosf(0.5f*p[2], &sn, &cs);
  apply_real(s, qb, cs, -sn, sn, cs);
}

extern "C" __global__ void __launch_bounds__(64)
k_qcnn(const float* __restrict__ inputs,
       const float* __restrict__ c1, const float* __restrict__ p1,
       const float* __restrict__ c2, const float* __restrict__ p2,
       const float* __restrict__ c3, const float* __restrict__ p3,
       const float* __restrict__ w_smp,
       float* __restrict__ out, int B)
{
  const int lane = threadIdx.x;
  const int b = blockIdx.x;
  float2 s[4];
  s[0] = make_float2(0.f,0.f); s[1]=s[0]; s[2]=s[0]; s[3]=s[0];
  if (lane == 0) s[0] = make_float2(1.f, 0.f);
  float xl[8];
  #pragma unroll
  for (int k=0;k<8;k++) xl[k] = inputs[b*8+k];
  const float R = 0.70710678118654752f;
  for (int rep=0;rep<2;rep++){
    for (int q=0;q<8;q++) apply_real(s, q, R, R, R, -R);
    for (int q=0;q<8;q++){
      float sn, cs; __sincosf(2.0f*xl[q], &sn, &cs);
      apply_diag(s, q, make_float2(1.f,0.f), make_float2(cs,sn));
    }
  }
  for (int k=0;k<4;k++) conv_g(s, 2*k, 2*k+1, c1+3*k);
  for (int k=0;k<4;k++) pool_g(s, k, k+4, p1+3*k);
  for (int k=0;k<2;k++) conv_g(s, 2*k, 2*k+1, c2+3*k);
  for (int k=0;k<2;k++) pool_g(s, k, k+2, p2+3*k);
  conv_g(s, 0, 1, c3);
  pool_g(s, 0, 1, p3);
  float v = (s[0].x*s[0].x + s[0].y*s[0].y) - (s[1].x*s[1].x + s[1].y*s[1].y)
          + (s[2].x*s[2].x + s[2].y*s[2].y) - (s[3].x*s[3].x + s[3].y*s[3].y);
  #pragma unroll
  for (int d=1; d<64; d<<=1) v += __shfl_xor(v, d);
  if (lane == 0){
    out[b] = v;
    float a00=1.f, a01=0.f, a10=0.f, a11=0.f;
    float sn, cs, t0, t1;
    #define RY0(T) { __sincosf(0.5f*(T), &sn, &cs); \
      t0 = cs*a00 - sn*a10; t1 = sn*a00 + cs*a10; a00=t0; a10=t1; \
      t0 = cs*a01 - sn*a11; t1 = sn*a01 + cs*a11; a01=t0; a11=t1; }
    #define RY1(T) { __sincosf(0.5f*(T), &sn, &cs); \
      t0 = cs*a00 - sn*a01; t1 = sn*a00 + cs*a01; a00=t0; a01=t1; \
      t0 = cs*a10 - sn*a11; t1 = sn*a10 + cs*a11; a10=t0; a11=t1; }
    #define CN01 { float tmp=a10; a10=a11; a11=tmp; }
    RY0(xl[0]); RY1(xl[1]); CN01;
    RY0(w_smp[0]); RY1(w_smp[1]); CN01;
    RY0(w_smp[2]); RY1(w_smp[3]);
    #undef RY0
    #undef RY1
    #undef CN01
    float* samp = out + B + B*10;
    samp[b*4+0] = a00*a00; samp[b*4+1] = a10*a10;
    samp[b*4+2] = a01*a01; samp[b*4+3] = a11*a11;
  }
}

// ---------------- tag head -------------------------------------------------
extern "C" __global__ void __launch_bounds__(256)
k_tag(const float* __restrict__ hs, const float* __restrict__ Wt,
      const float* __restrict__ bt, float* __restrict__ tag, int B)
{
  const int b = blockIdx.x*blockDim.x + threadIdx.x;
  if (b >= B) return;
  const float4* hp = (const float4*)(hs + b*16);
  const float4 h0=hp[0], h1=hp[1], h2=hp[2], h3=hp[3];
  float lg[10];
  #pragma unroll
  for (int j=0;j<10;j++){
    const float* w = Wt + j*16;
    float s0 = fmaf(w[0],h0.x, bt[j]); s0=fmaf(w[4],h1.x,s0); s0=fmaf(w[8],h2.x,s0);  s0=fmaf(w[12],h3.x,s0);
    float s1 = w[1]*h0.y;              s1=fmaf(w[5],h1.y,s1); s1=fmaf(w[9],h2.y,s1);  s1=fmaf(w[13],h3.y,s1);
    float s2 = w[2]*h0.z;              s2=fmaf(w[6],h1.z,s2); s2=fmaf(w[10],h2.z,s2); s2=fmaf(w[14],h3.z,s2);
    float s3 = w[3]*h0.w;              s3=fmaf(w[7],h1.w,s3); s3=fmaf(w[11],h2.w,s3); s3=fmaf(w[15],h3.w,s3);
    lg[j] = (s0+s1)+(s2+s3);
  }
  float m = lg[0];
  #pragma unroll
  for (int j=1;j<10;j++) m = fmaxf(m, lg[j]);
  float ss = 0.f;
  #pragma unroll
  for (int j=0;j<10;j++) ss += __expf(lg[j]-m);
  const float lse = __logf(ss) + m;
  #pragma unroll
  for (int j=0;j<10;j++) tag[b*10+j] = lg[j] - lse;
}

// ---------------------------------------------------------------------------
extern "C" void kernel_launch(void* const* d_in, const int* in_sizes, int n_in,
                              void* d_out, int out_size, void* d_ws, size_t ws_size,
                              hipStream_t stream)
{
  const float* inputs = (const float*)d_in[0];
  const float* c1  = (const float*)d_in[1];
  const float* p1  = (const float*)d_in[2];
  const float* c2  = (const float*)d_in[3];
  const float* p2  = (const float*)d_in[4];
  const float* c3  = (const float*)d_in[5];
  const float* p3  = (const float*)d_in[6];
  const float* wsm = (const float*)d_in[7];
  const float* Wf  = (const float*)d_in[8];
  const float* bf_ = (const float*)d_in[9];
  const float* Wi  = (const float*)d_in[10];
  const float* bi_ = (const float*)d_in[11];
  const float* Wu  = (const float*)d_in[12];
  const float* bu_ = (const float*)d_in[13];
  const float* Wo  = (const float*)d_in[14];
  const float* bo_ = (const float*)d_in[15];
  const float* thf = (const float*)d_in[16];
  const float* thi = (const float*)d_in[17];
  const float* thu = (const float*)d_in[18];
  const float* tho = (const float*)d_in[19];
  const float* Wt  = (const float*)d_in[20];
  const float* bt  = (const float*)d_in[21];
  const int B = in_sizes[0] / 8;          // 4096
  float* out = (float*)d_out;

  const size_t need = (size_t)(B*64 + B*16) * sizeof(float);  // 1.25 MiB
  if (ws_size >= need){
    float* axws = (float*)d_ws;
    float* wsh  = (float*)d_ws + (size_t)B*64;
    k_pre<<<B/4, 64, 0, stream>>>(inputs, Wf,Wi,Wu,Wo, bf_,bi_,bu_,bo_,
                                  thf,thi,thu,tho, axws, B);
    k_serial_ax<<<1, 64, 0, stream>>>(axws, Wf,Wi,Wu,Wo, wsh, B);
    k_qcnn<<<B, 64, 0, stream>>>(inputs, c1,p1,c2,p2,c3,p3, wsm, out, B);
    k_tag<<<(B+255)/256, 256, 0, stream>>>(wsh, Wt, bt, out + B, B);
  } else {
    float* wsh = (float*)d_ws;            // needs only 256 KiB
    k_serial_x<<<1, 64, 0, stream>>>(inputs, Wf,Wi,Wu,Wo, bf_,bi_,bu_,bo_,
                                     thf,thi,thu,tho, wsh, B);
    k_qcnn<<<B, 64, 0, stream>>>(inputs, c1,p1,c2,p2,c3,p3, wsm, out, B);
    k_tag<<<(B+255)/256, 256, 0, stream>>>(wsh, Wt, bt, out + B, B);
  }
}

// Round 5
// 825.709 us; speedup vs baseline: 2.1820x; 1.2428x over previous
//
#include <hip/hip_runtime.h>
#include <math.h>

// ---------------------------------------------------------------------------
// QCNN+QLSTM+QSampler forward, R5.
//   out: [0,B) qcnn | [B,11B) tag | [11B,15B) samp
//   ws : [0, B*64) ax (float, [B/4][64] float4 layout)  |  [B*64, B*80) h
// R5: serial step shrunk ~96 -> ~64 VALU ops:
//   - matvec: 3 base rotations + v_fmac_f32_dpp (ror:1/2/3 folded into FMA)
//   - prefix product: in-place v_mul_f32_dpp (1 instr/level)
//   - v[0] = p15 * rcp(c0) replaces the 4-level suffix chain
// ---------------------------------------------------------------------------

typedef unsigned int uint32x2 __attribute__((ext_vector_type(2)));

__device__ __forceinline__ float2 cmulf(float2 a, float2 b){
  return make_float2(a.x*b.x - a.y*b.y, a.x*b.y + a.y*b.x);
}
template<int CTRL>
__device__ __forceinline__ float dpp_mov(float v){
  return __int_as_float(__builtin_amdgcn_update_dpp(
      0, __float_as_int(v), CTRL, 0xF, 0xF, false));
}
// row_shl:D = 0x100|D, row_shr:D = 0x110|D, row_ror:D = 0x120|D

// in-place prefix-product level: p = dpp(p)*p on valid lanes, p kept on OOB
// (bound_ctrl omitted -> old-preserve; preserved p == p*1, the identity)
#define PFX_LEVEL(p, CTRLSTR) \
  asm("v_mul_f32_dpp %0, %0, %0 " CTRLSTR " row_mask:0xf bank_mask:0xf" : "+v"(p))

// acc += dpp_ror:D(src) * w   (ror has no OOB lanes -> no bound_ctrl needed)
#define FMAC_DPP(acc, src, w, CTRLSTR) \
  asm("v_fmac_f32_dpp %0, %1, %2 " CTRLSTR " row_mask:0xf bank_mask:0xf" \
      : "+v"(acc) : "v"(src), "v"(w))

// ---------------- serial LSTM step ----------------------------------------
struct SerState {
  float wh[16];
  float esc, gA, gB;
  int   e;
  bool  c32, c16, b0, b1, mQ, selq1;
};

__device__ __forceinline__ void lstm_step(const SerState& S, float ax,
                                          float& cx, float& h){
  // ---- matvec: rotations via 3 base movs + fmac_dpp -----------------------
  const float r0  = h;                 // rotation 0
  const float r4  = dpp_mov<0x124>(r0);
  const float r8  = dpp_mov<0x124>(r4);
  const float r12 = dpp_mov<0x124>(r8);
  float a0 = fmaf(S.wh[0],  r0,  ax);
  float a1 = S.wh[4]  * r4;
  float a2 = S.wh[8]  * r8;
  float a3 = S.wh[12] * r12;
  FMAC_DPP(a0, r0,  S.wh[1],  "row_ror:1");
  FMAC_DPP(a1, r4,  S.wh[5],  "row_ror:1");
  FMAC_DPP(a2, r8,  S.wh[9],  "row_ror:1");
  FMAC_DPP(a3, r12, S.wh[13], "row_ror:1");
  FMAC_DPP(a0, r0,  S.wh[2],  "row_ror:2");
  FMAC_DPP(a1, r4,  S.wh[6],  "row_ror:2");
  FMAC_DPP(a2, r8,  S.wh[10], "row_ror:2");
  FMAC_DPP(a3, r12, S.wh[14], "row_ror:2");
  FMAC_DPP(a0, r0,  S.wh[3],  "row_ror:3");
  FMAC_DPP(a1, r4,  S.wh[7],  "row_ror:3");
  FMAC_DPP(a2, r8,  S.wh[11], "row_ror:3");
  FMAC_DPP(a3, r12, S.wh[15], "row_ror:3");
  const float acc = (a0+a1) + (a2+a3);      // ax already holds b+theta+wx.x

  // ---- qlayer: v[e>=1] = prod_{0..e} c ; v[0] = p15 * rcp(c0) -------------
  const float c  = __cosf(acc);
  const float rc = __builtin_amdgcn_rcpf(c);     // off critical path
  float p = c;
  PFX_LEVEL(p, "row_shr:1");
  PFX_LEVEL(p, "row_shr:2");
  PFX_LEVEL(p, "row_shr:4");
  PFX_LEVEL(p, "row_shr:8");
  const float q1  = dpp_mov<0x121>(p);           // ror:1  candidate
  const float qF  = dpp_mov<0x12F>(p);           // ror:15 candidate
  const float p15 = S.selq1 ? q1 : qF;           // p[15] at lane e==0
  const float v   = (S.e==0) ? p15*rc : p;

  // ---- activation: sigmoid (f,i,o) / tanh (u), one exp2+rcp ---------------
  const float ex  = __builtin_amdgcn_exp2f(v * S.esc);
  const float sg  = __builtin_amdgcn_rcpf(1.0f + ex);
  const float act = fmaf(S.gA, sg, S.gB);

  // ---- gate gather: permlane swaps + fixed per-lane selects ---------------
  const unsigned au = __float_as_uint(act);
  uint32x2 r32 = __builtin_amdgcn_permlane32_swap(au, au, false, false);
  const unsigned o32u = S.c32 ? r32[0] : r32[1];          // dist 2
  uint32x2 rA = __builtin_amdgcn_permlane16_swap(au, au, false, false);
  const unsigned oAu = S.c16 ? rA[0] : rA[1];             // dist 1
  uint32x2 rB = __builtin_amdgcn_permlane16_swap(o32u, o32u, false, false);
  const unsigned oBu = S.c16 ? rB[0] : rB[1];             // dist 3
  const float fau = __uint_as_float(au);
  const float fA  = __uint_as_float(oAu);
  const float f32 = __uint_as_float(o32u);
  const float fB  = __uint_as_float(oBu);
  // gate k's value sits at xor-distance (g^k)
  const float pLoA = S.b0 ? fA  : fau;
  const float pHiA = S.b0 ? fB  : f32;
  const float act0 = S.b1 ? pHiA : pLoA;                  // f  (k=0)
  const float pLoB = S.b0 ? fau : fA;
  const float pHiB = S.b0 ? f32 : fB;
  const float act3 = S.b1 ? pLoB : pHiB;                  // o  (k=3)
  const float Q    = S.mQ ? fA*f32 : fau*fB;              // i*u

  // ---- state update -------------------------------------------------------
  cx = fmaf(act0, cx, Q);
  const float em = __builtin_amdgcn_exp2f(cx * -2.885390082f);
  const float rr = __builtin_amdgcn_rcpf(1.0f + em);
  h = fmaf(act3+act3, rr, -act3);             // o * tanh(cx)
}

__device__ __forceinline__ void ser_init(SerState& S, int lane,
    const float* Wf, const float* Wi, const float* Wu, const float* Wo){
  const int g = lane >> 4, e = lane & 15;
  S.e = e;
  const float* W = (g==0)?Wf:(g==1)?Wi:(g==2)?Wu:Wo;
  // ror direction probe: after ror:1 register holds value from lane (e+sgn)&15
  int probe = __builtin_amdgcn_update_dpp(0, e, 0x121, 0xF, 0xF, false);
  const int sgn = (probe == ((e+1)&15)) ? 1 : -1;
  S.selq1 = (sgn == -1);        // ror:1 moves lane15 -> lane0 when sgn==-1
  #pragma unroll
  for (int d=0; d<16; d++) S.wh[d] = W[e*24 + 8 + ((e + sgn*d + 32) & 15)];
  S.esc = (g==2) ? -2.885390082f : -1.442695041f;
  S.gA  = (g==2) ? 2.0f : 1.0f;
  S.gB  = (g==2) ? -1.0f : 0.0f;
  // permlane orientation probes (cndmask bools, fixed per lane)
  uint32x2 p32 = __builtin_amdgcn_permlane32_swap((unsigned)lane,(unsigned)lane,false,false);
  S.c32 = (p32[0] == (unsigned)(lane ^ 32));
  uint32x2 p16 = __builtin_amdgcn_permlane16_swap((unsigned)lane,(unsigned)lane,false,false);
  S.c16 = (p16[0] == (unsigned)(lane ^ 16));
  S.b0 = (g & 1) != 0;
  S.b1 = (g & 2) != 0;
  S.mQ = (g==0) || (g==3);
}

// ---------------- k_pre: ax[t][lane] = b[e]+th[e]+wx.x[t] ------------------
extern "C" __global__ void __launch_bounds__(64)
k_pre(const float* __restrict__ inputs,
      const float* __restrict__ Wf, const float* __restrict__ Wi,
      const float* __restrict__ Wu, const float* __restrict__ Wo,
      const float* __restrict__ bfv, const float* __restrict__ biv,
      const float* __restrict__ buv, const float* __restrict__ bov,
      const float* __restrict__ thf, const float* __restrict__ thi,
      const float* __restrict__ thu, const float* __restrict__ tho,
      float* __restrict__ axws, int B)
{
  const int lane = threadIdx.x, g = lane>>4, e = lane&15;
  const float* W  = (g==0)?Wf :(g==1)?Wi :(g==2)?Wu :Wo;
  const float* bb = (g==0)?bfv:(g==1)?biv:(g==2)?buv:bov;
  const float* th = (g==0)?thf:(g==1)?thi:(g==2)?thu:tho;
  float wx[8];
  #pragma unroll
  for (int k=0;k<8;k++) wx[k] = W[e*24+k];
  const float base = bb[e] + th[e];
  const int t0 = blockIdx.x * 4;
  float4 r;
  #pragma unroll
  for (int q=0;q<4;q++){
    const float4 xa = *(const float4*)(inputs + (t0+q)*8);
    const float4 xb = *(const float4*)(inputs + (t0+q)*8 + 4);
    float a = fmaf(wx[0], xa.x, base);
    a = fmaf(wx[1], xa.y, a); a = fmaf(wx[2], xa.z, a); a = fmaf(wx[3], xa.w, a);
    a = fmaf(wx[4], xb.x, a); a = fmaf(wx[5], xb.y, a);
    a = fmaf(wx[6], xb.z, a); a = fmaf(wx[7], xb.w, a);
    (&r.x)[q] = a;
  }
  ((float4*)axws)[blockIdx.x*64 + lane] = r;   // [B/4][64] float4
}

// ---------------- k_serial: the scan, ax from ws ---------------------------
extern "C" __global__ void __launch_bounds__(64)
k_serial_ax(const float* __restrict__ axws,
            const float* __restrict__ Wf, const float* __restrict__ Wi,
            const float* __restrict__ Wu, const float* __restrict__ Wo,
            float* __restrict__ wsh, int B)
{
  const int lane = threadIdx.x;
  SerState S; ser_init(S, lane, Wf, Wi, Wu, Wo);
  const float4* axp = (const float4*)axws;
  float4 cb0 = axp[lane], cb1 = axp[64+lane], cb2 = axp[128+lane], cb3 = axp[192+lane];
  float cx = 0.f, h = 0.f, hq0 = 0.f, hq1 = 0.f, hq2 = 0.f;
  for (int t0 = 0; t0 < B; t0 += 16){
    const int nq = (t0+16 < B) ? ((t0+16) >> 2) : (t0 >> 2);
    float4 nb0 = axp[(nq+0)*64 + lane];
    float4 nb1 = axp[(nq+1)*64 + lane];
    float4 nb2 = axp[(nq+2)*64 + lane];
    float4 nb3 = axp[(nq+3)*64 + lane];
    #pragma unroll
    for (int j=0; j<16; j++){
      const float4 cb = (j>>2)==0 ? cb0 : (j>>2)==1 ? cb1 : (j>>2)==2 ? cb2 : cb3;
      const float ax = (j&3)==0 ? cb.x : (j&3)==1 ? cb.y : (j&3)==2 ? cb.z : cb.w;
      lstm_step(S, ax, cx, h);
      if      ((j&3)==0) hq0 = h;
      else if ((j&3)==1) hq1 = h;
      else if ((j&3)==2) hq2 = h;
      else {
        // lane g*16+e stores step t0+j-3+g, elem e: addr collapses to +lane
        const float hv = S.b1 ? (S.b0 ? h : hq2) : (S.b0 ? hq1 : hq0);
        wsh[(t0+j-3)*16 + lane] = hv;          // 256B fully coalesced
      }
    }
    cb0 = nb0; cb1 = nb1; cb2 = nb2; cb3 = nb3;
  }
}

// ---------------- fallback serial (inline x) if ws too small ---------------
extern "C" __global__ void __launch_bounds__(64)
k_serial_x(const float* __restrict__ inputs,
           const float* __restrict__ Wf, const float* __restrict__ Wi,
           const float* __restrict__ Wu, const float* __restrict__ Wo,
           const float* __restrict__ bfv, const float* __restrict__ biv,
           const float* __restrict__ buv, const float* __restrict__ bov,
           const float* __restrict__ thf, const float* __restrict__ thi,
           const float* __restrict__ thu, const float* __restrict__ tho,
           float* __restrict__ wsh, int B)
{
  const int lane = threadIdx.x, g = lane>>4, e = lane&15;
  SerState S; ser_init(S, lane, Wf, Wi, Wu, Wo);
  const float* W  = (g==0)?Wf :(g==1)?Wi :(g==2)?Wu :Wo;
  const float* bb = (g==0)?bfv:(g==1)?biv:(g==2)?buv:bov;
  const float* th = (g==0)?thf:(g==1)?thi:(g==2)?thu:tho;
  float wx[8];
  #pragma unroll
  for (int k=0;k<8;k++) wx[k] = W[e*24+k];
  const float base = bb[e] + th[e];
  float cx=0.f, h=0.f, hq0=0.f, hq1=0.f, hq2=0.f;
  float4 xA = *(const float4*)(inputs),     xB = *(const float4*)(inputs+4);
  float4 yA = *(const float4*)(inputs+8),   yB = *(const float4*)(inputs+12);
  for (int t=0; t<B; t++){
    int tn = t+2; if (tn > B-1) tn = B-1;
    float4 zA = *(const float4*)(inputs + tn*8);
    float4 zB = *(const float4*)(inputs + tn*8 + 4);
    float a = fmaf(wx[0], xA.x, base);
    a = fmaf(wx[1], xA.y, a); a = fmaf(wx[2], xA.z, a); a = fmaf(wx[3], xA.w, a);
    a = fmaf(wx[4], xB.x, a); a = fmaf(wx[5], xB.y, a);
    a = fmaf(wx[6], xB.z, a); a = fmaf(wx[7], xB.w, a);
    lstm_step(S, a, cx, h);
    const int q = t & 3;
    if      (q==0) hq0 = h;
    else if (q==1) hq1 = h;
    else if (q==2) hq2 = h;
    else {
      const float hv = S.b1 ? (S.b0 ? h : hq2) : (S.b0 ? hq1 : hq0);
      wsh[(t-3)*16 + lane] = hv;
    }
    xA = yA; xB = yB; yA = zA; yB = zB;
  }
}

// ---------------- QCNN statevector helpers ---------------------------------
__device__ __forceinline__ void apply_diag(float2 (&s)[4], int q, float2 d0, float2 d1){
  const int lane = threadIdx.x;
  #pragma unroll
  for (int r=0;r<4;r++){
    int bit = (q>=6) ? ((r >> (7-q)) & 1) : ((lane >> (5-q)) & 1);
    s[r] = cmulf(s[r], bit ? d1 : d0);
  }
}
__device__ __forceinline__ void apply_real(float2 (&s)[4], int q,
                                           float m00, float m01, float m10, float m11){
  const int lane = threadIdx.x;
  if (q >= 6){
    const int st = 1 << (7-q);
    for (int base=0;base<4;base++){
      if (base & st) continue;
      float2 a = s[base], b2 = s[base+st];
      s[base]    = make_float2(fmaf(m00,a.x, m01*b2.x), fmaf(m00,a.y, m01*b2.y));
      s[base+st] = make_float2(fmaf(m10,a.x, m11*b2.x), fmaf(m10,a.y, m11*b2.y));
    }
  } else {
    const int mask = 1 << (5-q);
    const bool hi = (lane & mask) != 0;
    #pragma unroll
    for (int r=0;r<4;r++){
      float ox = __shfl_xor(s[r].x, mask);
      float oy = __shfl_xor(s[r].y, mask);
      float2 m = s[r];
      if (!hi) s[r] = make_float2(fmaf(m00,m.x, m01*ox), fmaf(m00,m.y, m01*oy));
      else     s[r] = make_float2(fmaf(m10,ox, m11*m.x), fmaf(m10,oy, m11*m.y));
    }
  }
}
__device__ __forceinline__ void cnot_g(float2 (&s)[4], int c, int t){
  const int lane = threadIdx.x;
  if (t >= 6){
    const int st = 1 << (7-t);
    for (int base=0;base<4;base++){
      if (base & st) continue;
      int cb = (c>=6) ? ((base >> (7-c)) & 1) : ((lane >> (5-c)) & 1);
      if (cb){ float2 tmp=s[base]; s[base]=s[base+st]; s[base+st]=tmp; }
    }
  } else {
    const int mask = 1 << (5-t);
    #pragma unroll
    for (int r=0;r<4;r++){
      float ox = __shfl_xor(s[r].x, mask);
      float oy = __shfl_xor(s[r].y, mask);
      int cb = (c>=6) ? ((r >> (7-c)) & 1) : ((lane >> (5-c)) & 1);
      if (cb) s[r] = make_float2(ox, oy);
    }
  }
}
__device__ void conv_g(float2 (&s)[4], int qa, int qb, const float* p){
  const float R = 0.70710678118654752f;
  apply_diag(s, qb, make_float2(R,R), make_float2(R,-R));
  cnot_g(s, qb, qa);
  float sn, cs;
  __sincosf(0.5f*p[0], &sn, &cs);
  apply_diag(s, qa, make_float2(cs,-sn), make_float2(cs,sn));
  __sincosf(0.5f*p[1], &sn, &cs);
  apply_real(s, qb, cs, -sn, sn, cs);
  cnot_g(s, qa, qb);
  __sincosf(0.5f*p[2], &sn, &cs);
  apply_real(s, qb, cs, -sn, sn, cs);
  cnot_g(s, qb, qa);
  apply_diag(s, qa, make_float2(R,-R), make_float2(R,R));
}
__device__ void pool_g(float2 (&s)[4], int qa, int qb, const float* p){
  const float R = 0.70710678118654752f;
  apply_diag(s, qb, make_float2(R,R), make_float2(R,-R));
  cnot_g(s, qb, qa);
  float sn, cs;
  __sincosf(0.5f*p[0], &sn, &cs);
  apply_diag(s, qa, make_float2(cs,-sn), make_float2(cs,sn));
  __sincosf(0.5f*p[1], &sn, &cs);
  apply_real(s, qb, cs, -sn, sn, cs);
  cnot_g(s, qa, qb);
  __sincosf(0.5f*p[2], &sn, &cs);
  apply_real(s, qb, cs, -sn, sn, cs);
}

extern "C" __global__ void __launch_bounds__(64)
k_qcnn(const float* __restrict__ inputs,
       const float* __restrict__ c1, const float* __restrict__ p1,
       const float* __restrict__ c2, const float* __restrict__ p2,
       const float* __restrict__ c3, const float* __restrict__ p3,
       const float* __restrict__ w_smp,
       float* __restrict__ out, int B)
{
  const int lane = threadIdx.x;
  const int b = blockIdx.x;
  float2 s[4];
  s[0] = make_float2(0.f,0.f); s[1]=s[0]; s[2]=s[0]; s[3]=s[0];
  if (lane == 0) s[0] = make_float2(1.f, 0.f);
  float xl[8];
  #pragma unroll
  for (int k=0;k<8;k++) xl[k] = inputs[b*8+k];
  const float R = 0.70710678118654752f;
  for (int rep=0;rep<2;rep++){
    for (int q=0;q<8;q++) apply_real(s, q, R, R, R, -R);
    for (int q=0;q<8;q++){
      float sn, cs; __sincosf(2.0f*xl[q], &sn, &cs);
      apply_diag(s, q, make_float2(1.f,0.f), make_float2(cs,sn));
    }
  }
  for (int k=0;k<4;k++) conv_g(s, 2*k, 2*k+1, c1+3*k);
  for (int k=0;k<4;k++) pool_g(s, k, k+4, p1+3*k);
  for (int k=0;k<2;k++) conv_g(s, 2*k, 2*k+1, c2+3*k);
  for (int k=0;k<2;k++) pool_g(s, k, k+2, p2+3*k);
  conv_g(s, 0, 1, c3);
  pool_g(s, 0, 1, p3);
  float v = (s[0].x*s[0].x + s[0].y*s[0].y) - (s[1].x*s[1].x + s[1].y*s[1].y)
          + (s[2].x*s[2].x + s[2].y*s[2].y) - (s[3].x*s[3].x + s[3].y*s[3].y);
  #pragma unroll
  for (int d=1; d<64; d<<=1) v += __shfl_xor(v, d);
  if (lane == 0){
    out[b] = v;
    float a00=1.f, a01=0.f, a10=0.f, a11=0.f;
    float sn, cs, t0, t1;
    #define RY0(T) { __sincosf(0.5f*(T), &sn, &cs); \
      t0 = cs*a00 - sn*a10; t1 = sn*a00 + cs*a10; a00=t0; a10=t1; \
      t0 = cs*a01 - sn*a11; t1 = sn*a01 + cs*a11; a01=t0; a11=t1; }
    #define RY1(T) { __sincosf(0.5f*(T), &sn, &cs); \
      t0 = cs*a00 - sn*a01; t1 = sn*a00 + cs*a01; a00=t0; a01=t1; \
      t0 = cs*a10 - sn*a11; t1 = sn*a10 + cs*a11; a10=t0; a11=t1; }
    #define CN01 { float tmp=a10; a10=a11; a11=tmp; }
    RY0(xl[0]); RY1(xl[1]); CN01;
    RY0(w_smp[0]); RY1(w_smp[1]); CN01;
    RY0(w_smp[2]); RY1(w_smp[3]);
    #undef RY0
    #undef RY1
    #undef CN01
    float* samp = out + B + B*10;
    samp[b*4+0] = a00*a00; samp[b*4+1] = a10*a10;
    samp[b*4+2] = a01*a01; samp[b*4+3] = a11*a11;
  }
}

// ---------------- tag head -------------------------------------------------
extern "C" __global__ void __launch_bounds__(256)
k_tag(const float* __restrict__ hs, const float* __restrict__ Wt,
      const float* __restrict__ bt, float* __restrict__ tag, int B)
{
  const int b = blockIdx.x*blockDim.x + threadIdx.x;
  if (b >= B) return;
  const float4* hp = (const float4*)(hs + b*16);
  const float4 h0=hp[0], h1=hp[1], h2=hp[2], h3=hp[3];
  float lg[10];
  #pragma unroll
  for (int j=0;j<10;j++){
    const float* w = Wt + j*16;
    float s0 = fmaf(w[0],h0.x, bt[j]); s0=fmaf(w[4],h1.x,s0); s0=fmaf(w[8],h2.x,s0);  s0=fmaf(w[12],h3.x,s0);
    float s1 = w[1]*h0.y;              s1=fmaf(w[5],h1.y,s1); s1=fmaf(w[9],h2.y,s1);  s1=fmaf(w[13],h3.y,s1);
    float s2 = w[2]*h0.z;              s2=fmaf(w[6],h1.z,s2); s2=fmaf(w[10],h2.z,s2); s2=fmaf(w[14],h3.z,s2);
    float s3 = w[3]*h0.w;              s3=fmaf(w[7],h1.w,s3); s3=fmaf(w[11],h2.w,s3); s3=fmaf(w[15],h3.w,s3);
    lg[j] = (s0+s1)+(s2+s3);
  }
  float m = lg[0];
  #pragma unroll
  for (int j=1;j<10;j++) m = fmaxf(m, lg[j]);
  float ss = 0.f;
  #pragma unroll
  for (int j=0;j<10;j++) ss += __expf(lg[j]-m);
  const float lse = __logf(ss) + m;
  #pragma unroll
  for (int j=0;j<10;j++) tag[b*10+j] = lg[j] - lse;
}

// ---------------------------------------------------------------------------
extern "C" void kernel_launch(void* const* d_in, const int* in_sizes, int n_in,
                              void* d_out, int out_size, void* d_ws, size_t ws_size,
                              hipStream_t stream)
{
  const float* inputs = (const float*)d_in[0];
  const float* c1  = (const float*)d_in[1];
  const float* p1  = (const float*)d_in[2];
  const float* c2  = (const float*)d_in[3];
  const float* p2  = (const float*)d_in[4];
  const float* c3  = (const float*)d_in[5];
  const float* p3  = (const float*)d_in[6];
  const float* wsm = (const float*)d_in[7];
  const float* Wf  = (const float*)d_in[8];
  const float* bf_ = (const float*)d_in[9];
  const float* Wi  = (const float*)d_in[10];
  const float* bi_ = (const float*)d_in[11];
  const float* Wu  = (const float*)d_in[12];
  const float* bu_ = (const float*)d_in[13];
  const float* Wo  = (const float*)d_in[14];
  const float* bo_ = (const float*)d_in[15];
  const float* thf = (const float*)d_in[16];
  const float* thi = (const float*)d_in[17];
  const float* thu = (const float*)d_in[18];
  const float* tho = (const float*)d_in[19];
  const float* Wt  = (const float*)d_in[20];
  const float* bt  = (const float*)d_in[21];
  const int B = in_sizes[0] / 8;          // 4096
  float* out = (float*)d_out;

  const size_t need = (size_t)(B*64 + B*16) * sizeof(float);  // 1.25 MiB
  if (ws_size >= need){
    float* axws = (float*)d_ws;
    float* wsh  = (float*)d_ws + (size_t)B*64;
    k_pre<<<B/4, 64, 0, stream>>>(inputs, Wf,Wi,Wu,Wo, bf_,bi_,bu_,bo_,
                                  thf,thi,thu,tho, axws, B);
    k_serial_ax<<<1, 64, 0, stream>>>(axws, Wf,Wi,Wu,Wo, wsh, B);
    k_qcnn<<<B, 64, 0, stream>>>(inputs, c1,p1,c2,p2,c3,p3, wsm, out, B);
    k_tag<<<(B+255)/256, 256, 0, stream>>>(wsh, Wt, bt, out + B, B);
  } else {
    float* wsh = (float*)d_ws;            // needs only 256 KiB
    k_serial_x<<<1, 64, 0, stream>>>(inputs, Wf,Wi,Wu,Wo, bf_,bi_,bu_,bo_,
                                     thf,thi,thu,tho, wsh, B);
    k_qcnn<<<B, 64, 0, stream>>>(inputs, c1,p1,c2,p2,c3,p3, wsm, out, B);
    k_tag<<<(B+255)/256, 256, 0, stream>>>(wsh, Wt, bt, out + B, B);
  }
}